// Round 11
// baseline (1035.725 us; speedup 1.0000x reference)
//
#include <hip/hip_runtime.h>
#include <hip/hip_cooperative_groups.h>
#include <math.h>

namespace cg = cooperative_groups;

typedef unsigned int u32;
typedef unsigned long long u64;
typedef unsigned short ushort_t;

typedef __attribute__((ext_vector_type(8))) short short8;
typedef __attribute__((ext_vector_type(16))) float f32x16;

#define KANC 18376
#define PRE 2000
#define PREP 2048
#define POST 300

#define OUT_CLS 0
#define OUT_REG 73504
#define OUT_ROI 220512
#define OUT_RID 222912
#define OUT_ANC 223512

// ws byte offsets
#define WS_NHWC   0u
#define WS_FT     16777216u
#define WS_W3     41943040u
#define WS_VPOS   56098816u
#define WS_BOXES  56246272u
#define WS_KEYS   56834304u
#define WS_TOPBOX 56981312u
#define WS_TOPKEY 57046848u
#define WS_MASK   57063232u

#define A_SPL2 7920   // k1 LDS ushorts per split (3 rows x 66 xi x 40)
#define SMEM_BYTES 47520

__device__ __forceinline__ ushort_t f2bf(float f) {
    u32 u = __float_as_uint(f);
    u32 r = (u + 0x7FFFu + ((u >> 16) & 1u)) >> 16;
    return (ushort_t)r;
}
__device__ __forceinline__ float bf2f(ushort_t h) {
    return __uint_as_float(((u32)h) << 16);
}
__device__ __forceinline__ u32 pack3(float v0, float v1, ushort_t* m0, ushort_t* m1,
                                     ushort_t* l0, ushort_t* l1) {
    ushort_t h0 = f2bf(v0);
    float r = v0 - bf2f(h0);
    *m0 = f2bf(r);
    *l0 = f2bf(r - bf2f(*m0));
    ushort_t h1 = f2bf(v1);
    float r1 = v1 - bf2f(h1);
    *m1 = f2bf(r1);
    *l1 = f2bf(r1 - bf2f(*m1));
    return (u32)h0 | ((u32)h1 << 16);
}

// hardcoded correctly-rounded doubles: sqrt(0.5), 1, sqrt(2)
__device__ __forceinline__ void anchor_base(int t, float& y1, float& x1, float& y2, float& x2) {
    const double SQ[3] = {0.7071067811865476, 1.0, 1.4142135623730951};
    const double SC[3] = {8.0, 16.0, 32.0};
    int ri = t / 3, si = t % 3;
    double h = 16.0 * SC[si] * SQ[ri];
    double w = 16.0 * SC[si] * SQ[2 - ri];
    y1 = (float)(8.0 - h * 0.5);
    x1 = (float)(8.0 - w * 0.5);
    y2 = (float)(8.0 + h * 0.5);
    x2 = (float)(8.0 + w * 0.5);
}

// suffix sums at 256 threads, N <= 2048
__device__ __forceinline__ void suffix_scan256(u32* suf, const u32* hist, int N, int tid) {
    for (int i = tid; i < N; i += 256) suf[i] = hist[i];
    if (tid == 0) suf[N] = 0;
    __syncthreads();
    for (int off = 1; off < N; off <<= 1) {
        u32 add[8];
        int c = 0;
        for (int i = tid; i < N; i += 256) { add[c++] = (i + off < N) ? suf[i + off] : 0; }
        __syncthreads();
        c = 0;
        for (int i = tid; i < N; i += 256) { suf[i] += add[c++]; }
        __syncthreads();
    }
}

// ==================== MEGA: entire pipeline, 1 cooperative launch ====================
// Grid 512 x 256, static LDS 47520B -> exactly 2 blocks/CU co-resident (512 = 2*256).
// Phases separated by grid.sync(); smem is a per-phase union.
__global__ __launch_bounds__(256, 2) void mega(
    const float* __restrict__ feat, const float* __restrict__ share_w,
    const float* __restrict__ share_b, const float* __restrict__ cls_w,
    const float* __restrict__ cls_b, const float* __restrict__ reg_w,
    const float* __restrict__ reg_b, const int* __restrict__ d_imgh,
    const int* __restrict__ d_imgw, float* __restrict__ out,
    float* __restrict__ nhwc, ushort_t* __restrict__ ft,
    ushort_t* __restrict__ w3, float* __restrict__ boxes_ws,
    u32* __restrict__ keys_ws, float* __restrict__ topbox,
    u32* __restrict__ topkey, u64* __restrict__ maskp)
{
    __shared__ __align__(16) unsigned char smem[SMEM_BYTES];
    cg::grid_group grid = cg::this_grid();
    int tid = threadIdx.x;
    int bid = blockIdx.x;

    // ---------------- Phase T: transforms + nhwc zero ----------------
    {
        float* lds = (float*)smem;
        for (int fu = 0; fu < 2; fu++) {
            int u = bid * 2 + fu;            // 0..1023 feat units
            float4 z4 = make_float4(0.f, 0.f, 0.f, 0.f);
            float4* nz = (float4*)nhwc + (size_t)u * 1024;
            for (int i = tid; i < 1024; i += 256) nz[i] = z4;
            int by = u >> 3; int b = by >> 6, y = by & 63;
            int ci0 = (u & 7) * 64;
            for (int it = 0; it < 16; it++) {
                int idx = it * 256 + tid;
                int ci = idx >> 6, x = idx & 63;
                lds[ci * 65 + x] = feat[((size_t)(b * 512 + ci0 + ci) * 64 + y) * 64 + x];
            }
            __syncthreads();
            const size_t spl = (size_t)2 * 64 * 64 * 512;
            u32* ft32 = (u32*)ft;
            for (int it = 0; it < 8; it++) {
                int idx = it * 256 + tid;
                int x = idx >> 5, cp = idx & 31;
                float v0 = lds[(2 * cp) * 65 + x];
                float v1 = lds[(2 * cp + 1) * 65 + x];
                ushort_t m0, m1, l0, l1;
                u32 hi = pack3(v0, v1, &m0, &m1, &l0, &l1);
                size_t base = ((size_t)(b * 64 + y) * 64 + x) * 512 + ci0 + 2 * cp;
                ft32[base >> 1] = hi;
                ft32[(base + spl) >> 1] = (u32)m0 | ((u32)m1 << 16);
                ft32[(base + 2 * spl) >> 1] = (u32)l0 | ((u32)l1 << 16);
            }
            __syncthreads();
        }
        {   // weight unit = bid (0..511)
            int cob = bid >> 3, cib = (bid & 7) * 64;
            for (int s = tid; s < 4608; s += 256) {
                int co = s / 576, r = s - co * 576;
                lds[co * 577 + r] = share_w[((size_t)(cob * 8 + co) * 512 + cib) * 9 + r];
            }
            __syncthreads();
            const size_t spl = (size_t)9 * 512 * 512;
            u32* w32 = (u32*)w3;
            int co = tid >> 5, cp = tid & 31;
            for (int kk = 0; kk < 9; kk++) {
                float v0 = lds[co * 577 + (2 * cp) * 9 + kk];
                float v1 = lds[co * 577 + (2 * cp + 1) * 9 + kk];
                ushort_t m0, m1, l0, l1;
                u32 hi = pack3(v0, v1, &m0, &m1, &l0, &l1);
                size_t base = ((size_t)kk * 512 + cob * 8 + co) * 512 + cib + 2 * cp;
                w32[base >> 1] = hi;
                w32[(base + spl) >> 1] = (u32)m0 | ((u32)m1 << 16);
                w32[(base + 2 * spl) >> 1] = (u32)l0 | ((u32)l1 << 16);
            }
        }
    }
    grid.sync();

    // ---------------- Phase K1: 3x3 conv (R9 body, defended optimum) ----------------
    {
        ushort_t* lds16 = (ushort_t*)smem;
        int nt = (bid >> 1) & 1;
        int kh = (bid >> 2) & 1;
        int mt = ((bid >> 3) << 1) | (bid & 1);
        int b = mt >> 6, y = mt & 63;
        int nb = nt << 8;
        int ct0 = kh * 8;

        int lane = tid & 63;
        int w = tid >> 6;
        int wn = w << 6;
        int nlane = lane & 31;
        int kgrp8 = (lane >> 5) * 8;

        const size_t FT_SPL = (size_t)2 * 64 * 64 * 512;
        const size_t W3_SPL = (size_t)9 * 512 * 512;

        int sx = tid >> 2;
        int sq = tid & 3;

        f32x16 acc[2];
        f32x16 acc2[2];
#pragma unroll
        for (int ni = 0; ni < 2; ni++)
#pragma unroll
            for (int r = 0; r < 16; r++) { acc[ni][r] = 0.0f; acc2[ni][r] = 0.0f; }

        if (tid < 72) {
            int s = tid / 24, rem = tid % 24;
            int r = rem >> 3, rem2 = rem & 7;
            int side = rem2 >> 2, q = rem2 & 3;
            uint4 z = make_uint4(0, 0, 0, 0);
            *(uint4*)&lds16[s * A_SPL2 + (r * 66 + side * 65) * 40 + q * 8] = z;
        }

        uint4 pbA[9];
        auto loadA = [&](int ct) {
#pragma unroll
            for (int r = 0; r < 3; r++) {
                int yy = y - 1 + r;
                bool valid = (yy >= 0 && yy < 64);
                size_t rowbase = ((size_t)(b * 64 + (valid ? yy : 0)) * 64 + sx) * 512 + ct * 32 + sq * 8;
#pragma unroll
                for (int s = 0; s < 3; s++) {
                    uint4 v = make_uint4(0, 0, 0, 0);
                    if (valid) v = *(const uint4*)&ft[rowbase + (size_t)s * FT_SPL];
                    pbA[r * 3 + s] = v;
                }
            }
        };
        auto writeA = [&]() {
#pragma unroll
            for (int r = 0; r < 3; r++)
#pragma unroll
                for (int s = 0; s < 3; s++)
                    *(uint4*)&lds16[s * A_SPL2 + (r * 66 + sx + 1) * 40 + sq * 8] = pbA[r * 3 + s];
        };

        short8 breg[2][2][3];
        auto loadB = [&](int buf, int tap, int ks, int ct) {
#pragma unroll
            for (int ni = 0; ni < 2; ni++) {
                size_t cobase = ((size_t)(tap * 512 + nb + wn + ni * 32 + nlane)) * 512
                                + ct * 32 + ks * 16 + kgrp8;
#pragma unroll
                for (int s = 0; s < 3; s++)
                    breg[buf][ni][s] = *(const short8*)&w3[(size_t)s * W3_SPL + cobase];
            }
        };

        loadA(ct0);
        loadB(0, 0, 0, ct0);

        for (int ct = ct0; ct < ct0 + 8; ct++) {
            __syncthreads();
            writeA();
            __syncthreads();
            if (ct + 1 < ct0 + 8) loadA(ct + 1);

#pragma unroll
            for (int u = 0; u < 18; u++) {
                int cur = u & 1, alt = cur ^ 1;
                if (u + 1 < 18) loadB(alt, (u + 1) >> 1, (u + 1) & 1, ct);
                else if (ct + 1 < ct0 + 8) loadB(alt, 0, 0, ct + 1);
                int tap = u >> 1, ks = u & 1;
                int ky = tap / 3, kx = tap - ky * 3;

                short8 af[3][2];
#pragma unroll
                for (int s = 0; s < 3; s++) {
#pragma unroll
                    for (int mi = 0; mi < 2; mi++)
                        af[s][mi] = *(const short8*)&lds16[s * A_SPL2 +
                            (ky * 66 + mi * 32 + nlane + kx) * 40 + ks * 16 + kgrp8];
                }
#pragma unroll
                for (int t = 0; t < 6; t++) {
                    const int sa_t[6] = {0, 0, 1, 0, 1, 2};
                    const int sb_t[6] = {0, 1, 0, 2, 1, 0};
                    int sa = sa_t[t], sb = sb_t[t];
#pragma unroll
                    for (int ni = 0; ni < 2; ni++) {
                        acc[ni]  = __builtin_amdgcn_mfma_f32_32x32x16_bf16(
                            af[sa][0], breg[cur][ni][sb], acc[ni], 0, 0, 0);
                        acc2[ni] = __builtin_amdgcn_mfma_f32_32x32x16_bf16(
                            af[sa][1], breg[cur][ni][sb], acc2[ni], 0, 0, 0);
                    }
                }
            }
        }

#pragma unroll
        for (int ni = 0; ni < 2; ni++) {
            int co = nb + wn + ni * 32 + nlane;
#pragma unroll
            for (int r = 0; r < 16; r++) {
                int xx = (r & 3) + 8 * (r >> 2) + 4 * (lane >> 5);
                atomicAdd(&nhwc[((size_t)(b * 64 + y) * 64 + xx) * 512 + co], acc[ni][r]);
                atomicAdd(&nhwc[((size_t)(b * 64 + y) * 64 + 32 + xx) * 512 + co], acc2[ni][r]);
            }
        }
    }
    grid.sync();

    // ---------------- Phase K2: heads + softmax + decode + keys + anchors ----------------
    {
        int row = bid >> 2;
        int b = row >> 6, y = row & 63;
        int q = bid & 3;
        int p0 = q * 16;
        float* Al = (float*)smem;            // 16*68 floats
        float* Wl = Al + 16 * 68;            // 64*64 floats
        float* Ob = Wl + 64 * 64;            // 54*16 floats  (total 24192B)
        int og = tid & 15, pg = tid >> 4;
        float acc[4];
#pragma unroll
        for (int j = 0; j < 4; j++) acc[j] = 0.0f;

        for (int cib = 0; cib < 512; cib += 64) {
            for (int s = tid; s < 1024; s += 256) {
                int kk = s & 63, pp = s >> 6;
                float v = nhwc[((size_t)(b * 64 + y) * 64 + p0 + pp) * 512 + cib + kk]
                          + share_b[cib + kk];
                Al[pp * 68 + kk] = fmaxf(v, 0.0f);
            }
            for (int s = tid; s < 64 * 64; s += 256) {
                int o = s >> 6, kk = s & 63;
                float wv = 0.0f;
                if (o < 18) wv = cls_w[o * 512 + cib + kk];
                else if (o < 54) wv = reg_w[(o - 18) * 512 + cib + kk];
                Wl[s] = wv;
            }
            __syncthreads();
            for (int kq = 0; kq < 16; kq++) {
                float4 a4 = *(const float4*)&Al[pg * 68 + kq * 4];
#pragma unroll
                for (int j = 0; j < 4; j++) {
                    float4 w4 = *(const float4*)&Wl[(og * 4 + j) * 64 + kq * 4];
                    acc[j] += a4.x * w4.x + a4.y * w4.y + a4.z * w4.z + a4.w * w4.w;
                }
            }
            __syncthreads();
        }
#pragma unroll
        for (int j = 0; j < 4; j++) {
            int o = og * 4 + j;
            if (o < 54) {
                float bvv = (o < 18) ? cls_b[o] : reg_b[o - 18];
                Ob[o * 16 + pg] = acc[j] + bvv;
            }
        }
        __syncthreads();
        float imgh = (float)d_imgh[0], imgw = (float)d_imgw[0];
        for (int task = tid; task < 144; task += 256) {
            int ta = task >> 4, p2 = task & 15;
            int x = p0 + p2;
            int a_idx = (y * 64 + x) * 9 + ta;
            int j = 0;
            bool myvalid = false;
#pragma unroll
            for (int tt = 0; tt < 9; tt++) {
                float c0, c1, c2, c3;
                anchor_base(tt, c0, c1, c2, c3);
                int ylo = (int)((-c0) / 16.0f) + 1;
                int yhi = (int)((imgh - c2) / 16.0f);
                int xlo = (int)((-c1) / 16.0f) + 1;
                int xhi = (int)((imgw - c3) / 16.0f);
                ylo = max(ylo, 0); yhi = min(yhi, 63);
                xlo = max(xlo, 0); xhi = min(xhi, 63);
                int Wt  = max(xhi - xlo + 1, 0);
                int nry = max(yhi - ylo + 1, 0);
                int rb  = min(max(y - ylo, 0), nry);
                bool vy = (y >= ylo) && (y <= yhi);
                int cb  = vy ? min(max(x - xlo, 0), Wt) : 0;
                bool val = vy && (x >= xlo) && (x <= xhi);
                j += rb * Wt + cb + ((tt < ta && val) ? 1 : 0);
                if (tt == ta) {
                    myvalid = val;
                    float4 o4;
                    o4.x = c0 + 16.0f * y;
                    o4.y = c1 + 16.0f * x;
                    o4.z = c2 + 16.0f * y;
                    o4.w = c3 + 16.0f * x;
                    *(float4*)&out[OUT_ANC + a_idx * 4] = o4;
                }
            }
            if (!myvalid) continue;
            float c0 = Ob[(2 * ta) * 16 + p2], c1 = Ob[(2 * ta + 1) * 16 + p2];
            float m = fmaxf(c0, c1);
            float e0 = expf(c0 - m), e1 = expf(c1 - m);
            float sden = e0 + e1;
            float p0v = e0 / sden, p1v = e1 / sden;
            out[OUT_CLS + (size_t)(b * KANC + j) * 2 + 0] = p0v;
            out[OUT_CLS + (size_t)(b * KANC + j) * 2 + 1] = p1v;
            float l0 = Ob[(18 + 4 * ta + 0) * 16 + p2];
            float l1 = Ob[(18 + 4 * ta + 1) * 16 + p2];
            float l2 = Ob[(18 + 4 * ta + 2) * 16 + p2];
            float l3 = Ob[(18 + 4 * ta + 3) * 16 + p2];
            out[OUT_REG + (size_t)(b * KANC + j) * 4 + 0] = l0;
            out[OUT_REG + (size_t)(b * KANC + j) * 4 + 1] = l1;
            out[OUT_REG + (size_t)(b * KANC + j) * 4 + 2] = l2;
            out[OUT_REG + (size_t)(b * KANC + j) * 4 + 3] = l3;
            float b0, b1, b2, b3; anchor_base(ta, b0, b1, b2, b3);
            float ay1 = b0 + 16.0f * y, ax1 = b1 + 16.0f * x;
            float ay2 = b2 + 16.0f * y, ax2 = b3 + 16.0f * x;
            float hh = ay2 - ay1, wdt = ax2 - ax1;
            float cy = ay1 + 0.5f * hh, cx = ax1 + 0.5f * wdt;
            float ncy = l0 * hh + cy, ncx = l1 * wdt + cx;
            float nh = hh * expf(l2), nw = wdt * expf(l3);
            float by1 = fminf(fmaxf(ncy - 0.5f * nh, 0.0f), imgh);
            float bx1 = fminf(fmaxf(ncx - 0.5f * nw, 0.0f), imgw);
            float by2 = fminf(fmaxf(ncy + 0.5f * nh, 0.0f), imgh);
            float bx2 = fminf(fmaxf(ncx + 0.5f * nw, 0.0f), imgw);
            boxes_ws[(size_t)(b * KANC + j) * 4 + 0] = by1;
            boxes_ws[(size_t)(b * KANC + j) * 4 + 1] = bx1;
            boxes_ws[(size_t)(b * KANC + j) * 4 + 2] = by2;
            boxes_ws[(size_t)(b * KANC + j) * 4 + 3] = bx2;
            float hs = by2 - by1, wsz = bx2 - bx1;
            u32 key = 0;
            if (hs >= 16.0f && wsz >= 16.0f) key = __float_as_uint(p1v) + 1u;
            keys_ws[b * KANC + j] = key;
        }
    }
    grid.sync();

    // ---------------- Phase K3: exact top-2000 (blocks 0,1; 256 threads) ----------------
    if (bid < 2) {
        int b = bid;
        const u32* keys = keys_ws + (size_t)b * KANC;
        u64* sbuf = (u64*)smem;                   // 2048 u64 = 16384B
        u32* hist = (u32*)(smem + 16384);         // 2048 u32
        u32* suf  = (u32*)(smem + 24576);         // 2049 u32
        int* PsP  = (int*)(smem + 32784);
        int* cntP = (int*)(smem + 32792);

        // level 1: bits [30:22] (512 bins), 8 private half-wave copies over sbuf
        u32* hist_p = (u32*)sbuf;
        int cpy = tid >> 5;
        for (int i = tid; i < 4096; i += 256) hist_p[i] = 0;
        __syncthreads();
        for (int i = tid; i < KANC; i += 256) atomicAdd(&hist_p[cpy * 512 + (keys[i] >> 22)], 1u);
        __syncthreads();
        for (int bin = tid; bin < 512; bin += 256) {
            u32 s = 0;
#pragma unroll
            for (int c = 0; c < 8; c++) s += hist_p[c * 512 + bin];
            hist[bin] = s;
        }
        __syncthreads();
        suffix_scan256(suf, hist, 512, tid);
        if (tid == 0) *PsP = 0;
        __syncthreads();
        for (int i = tid; i < 512; i += 256)
            if (suf[i] >= (u32)PRE && suf[i + 1] < (u32)PRE) *PsP = i;
        __syncthreads();
        u32 P1 = (u32)*PsP;
        u32 quota2 = (u32)PRE - suf[P1 + 1];
        __syncthreads();

        // level 2: bits [21:11] within P1
        for (int i = tid; i < 2048; i += 256) hist[i] = 0;
        __syncthreads();
        for (int i = tid; i < KANC; i += 256) {
            u32 k = keys[i];
            if ((k >> 22) == P1) atomicAdd(&hist[(k >> 11) & 2047u], 1u);
        }
        __syncthreads();
        suffix_scan256(suf, hist, 2048, tid);
        if (tid == 0) *PsP = 0;
        __syncthreads();
        for (int i = tid; i < 2048; i += 256)
            if (suf[i] >= quota2 && suf[i + 1] < quota2) *PsP = i;
        __syncthreads();
        u32 P2 = (u32)*PsP;
        u32 quota3 = quota2 - suf[P2 + 1];
        __syncthreads();

        // level 3: bits [10:0] within (P1,P2)
        u32 pref = (P1 << 11) | P2;
        for (int i = tid; i < 2048; i += 256) hist[i] = 0;
        __syncthreads();
        for (int i = tid; i < KANC; i += 256) {
            u32 k = keys[i];
            if ((k >> 11) == pref) atomicAdd(&hist[k & 2047u], 1u);
        }
        __syncthreads();
        suffix_scan256(suf, hist, 2048, tid);
        if (tid == 0) *PsP = 0;
        __syncthreads();
        for (int i = tid; i < 2048; i += 256)
            if (suf[i] >= quota3 && suf[i + 1] < quota3) *PsP = i;
        __syncthreads();
        u32 P3 = (u32)*PsP;
        u32 T = (P1 << 22) | (P2 << 11) | P3;
        u32 Tm = (T < 1u) ? 1u : T;

        // gather >= Tm with wave-aggregated atomics
        __syncthreads();
        for (int i = tid; i < 2048; i += 256) sbuf[i] = 0ull;
        if (tid == 0) *cntP = 0;
        __syncthreads();
        int lane = tid & 63;
        for (int i = tid; i < KANC + 255; i += 256) {
            u32 k = (i < KANC) ? keys[i] : 0u;
            bool p = (i < KANC) && (k >= Tm);
            u64 m = __ballot(p);
            if (m) {
                int ldr = __ffsll((unsigned long long)m) - 1;
                int base = 0;
                if (lane == ldr) base = atomicAdd(cntP, __popcll(m));
                base = __shfl(base, ldr);
                if (p) {
                    int pos = base + __popcll(m & ((1ull << lane) - 1ull));
                    if (pos < 2048)
                        sbuf[pos] = ((u64)k << 32) | (u64)(0xFFFFFFFFu - (u32)i);
                }
            }
        }
        __syncthreads();

        // bitonic sort descending, 2048 u64, 8 elems/thread/phase
        for (int k2 = 2; k2 <= 2048; k2 <<= 1) {
            for (int j2 = k2 >> 1; j2 > 0; j2 >>= 1) {
                for (int i = tid; i < 2048; i += 256) {
                    int ixj = i ^ j2;
                    if (ixj > i) {
                        u64 va = sbuf[i], vb = sbuf[ixj];
                        bool descRegion = ((i & k2) == 0);
                        if (descRegion ? (va < vb) : (va > vb)) {
                            sbuf[i] = vb; sbuf[ixj] = va;
                        }
                    }
                }
                __syncthreads();
            }
        }

        for (int i = tid; i < PREP; i += 256) {
            u64 v = sbuf[i];
            u32 kk = (u32)(v >> 32);
            u32 j = 0xFFFFFFFFu - (u32)(v & 0xFFFFFFFFull);
            bool good = (i < PRE) && (kk != 0);
            topkey[b * PREP + i] = good ? kk : 0;
            float4 bx = make_float4(0.0f, 0.0f, 0.0f, 0.0f);
            if (good) bx = *(const float4*)&boxes_ws[(size_t)(b * KANC + j) * 4];
            *(float4*)&topbox[(size_t)(b * PREP + i) * 4] = bx;
        }
    }
    grid.sync();

    // ---------------- Phase K4: NMS mask (one (b,ib,jb) per wave) ----------------
    {
        int w = tid >> 6, lane = tid & 63;
        int unit = bid * 4 + w;            // 0..2047
        int b = unit >> 10;
        int ib = (unit >> 5) & 31;
        int jb = unit & 31;
        if (jb < ib) {
            maskp[(size_t)(b * PREP + ib * 64 + lane) * 32 + jb] = 0ull;
        } else {
            float4 bi = *(const float4*)&topbox[(size_t)(b * PREP + ib * 64 + lane) * 4];
            float4 bj = *(const float4*)&topbox[(size_t)(b * PREP + jb * 64 + lane) * 4];
            float ai = (bi.z - bi.x) * (bi.w - bi.y);
            float aj = (bj.z - bj.x) * (bj.w - bj.y);
            u64 word = 0;
            for (int ii = 0; ii < 64; ii++) {
                float y1 = __shfl(bi.x, ii), x1 = __shfl(bi.y, ii);
                float y2 = __shfl(bi.z, ii), x2 = __shfl(bi.w, ii);
                float aii = __shfl(ai, ii);
                float yy1 = fmaxf(y1, bj.x), xx1 = fmaxf(x1, bj.y);
                float yy2 = fminf(y2, bj.z), xx2 = fminf(x2, bj.w);
                float inter = fmaxf(yy2 - yy1, 0.0f) * fmaxf(xx2 - xx1, 0.0f);
                float iou = inter / (aii + aj - inter + 1e-9f);
                u64 bal = __ballot(iou > 0.7f);
                if (lane == ii) word = bal;
            }
            maskp[(size_t)(b * PREP + ib * 64 + lane) * 32 + jb] = word;
        }
    }
    grid.sync();

    // ---------------- Phase K5: greedy scan (blocks 0,1; wave 0) ----------------
    if (bid < 2) {
        int b = bid;
        int* keptL = (int*)smem;
        int* nkP = (int*)(smem + 1280);
        if (tid < 64) {
            int lane = tid;
            u64 validw = 0;
            for (int it = 0; it < 32; it++) {
                u64 wv = __ballot(topkey[b * PREP + it * 64 + lane] != 0);
                if (lane == it) validw = wv;
            }
            const u64* mb = maskp + (size_t)b * PREP * 32;
            u64 remv = 0;
            const int CH = 16;
            u64 bufA[CH], bufB[CH];
            auto loadRows = [&](u64* buf, int base) {
#pragma unroll
                for (int k = 0; k < CH; k++)
                    buf[k] = (lane < 32) ? mb[(size_t)(base + k) * 32 + lane] : 0ull;
            };
            int nk = 0;
            auto process = [&](u64* buf, int base) {
                int wi = base >> 6, sh = base & 63;
                u64 supw = __shfl(remv, wi);
                u64 valw = __shfl(validw, wi);
                u32 cand = (u32)(((~supw & valw) >> sh) & 0xFFFFull);
                while (cand) {
                    int k = __builtin_ctz(cand);
                    cand &= cand - 1;
                    int i = base + k;
                    remv |= buf[k];
                    u64 rw = __shfl(buf[k], wi);
                    cand &= ~((u32)((rw >> sh) & 0xFFFFull));
                    if (lane == 0) keptL[nk] = i;
                    nk++;
                    if (nk == POST) break;
                }
            };
            loadRows(bufA, 0);
            for (int base = 0; base < PRE && nk < POST; base += 2 * CH) {
                loadRows(bufB, base + CH);
                process(bufA, base);
                if (nk < POST && base + CH < PRE) {
                    if (base + 2 * CH < PRE) loadRows(bufA, base + 2 * CH);
                    process(bufB, base + CH);
                }
            }
            if (lane == 0) *nkP = nk;
        }
        __syncthreads();
        int nk = *nkP;
        for (int s = tid; s < POST; s += 256) {
            float4 bx = make_float4(0.0f, 0.0f, 0.0f, 0.0f);
            if (s < nk) bx = *(const float4*)&topbox[(size_t)(b * PREP + keptL[s]) * 4];
            *(float4*)&out[OUT_ROI + (size_t)(b * POST + s) * 4] = bx;
            out[OUT_RID + b * POST + s] = (float)b;
        }
    }
}

// ==================== Fallback: R10 6-kernel pipeline (if coop launch rejected) ====================

__global__ __launch_bounds__(256) void t12_pre(const float* __restrict__ feat,
                                               const float* __restrict__ w,
                                               ushort_t* __restrict__ ft,
                                               ushort_t* __restrict__ w3,
                                               float* __restrict__ nhwc) {
    __shared__ float lds[8 * 577];
    int tid = threadIdx.x;
    int bid = blockIdx.x;
    if (bid < 1024) {
        float4 z4 = make_float4(0.f, 0.f, 0.f, 0.f);
        float4* nz = (float4*)nhwc + (size_t)bid * 1024;
        for (int i = tid; i < 1024; i += 256) nz[i] = z4;
        int by = bid >> 3;
        int b = by >> 6, y = by & 63;
        int ci0 = (bid & 7) * 64;
        for (int it = 0; it < 16; it++) {
            int idx = it * 256 + tid;
            int ci = idx >> 6, x = idx & 63;
            lds[ci * 65 + x] = feat[((size_t)(b * 512 + ci0 + ci) * 64 + y) * 64 + x];
        }
        __syncthreads();
        const size_t spl = (size_t)2 * 64 * 64 * 512;
        u32* ft32 = (u32*)ft;
        for (int it = 0; it < 8; it++) {
            int idx = it * 256 + tid;
            int x = idx >> 5, cp = idx & 31;
            float v0 = lds[(2 * cp) * 65 + x];
            float v1 = lds[(2 * cp + 1) * 65 + x];
            ushort_t m0, m1, l0, l1;
            u32 hi = pack3(v0, v1, &m0, &m1, &l0, &l1);
            size_t base = ((size_t)(b * 64 + y) * 64 + x) * 512 + ci0 + 2 * cp;
            ft32[base >> 1] = hi;
            ft32[(base + spl) >> 1] = (u32)m0 | ((u32)m1 << 16);
            ft32[(base + 2 * spl) >> 1] = (u32)l0 | ((u32)l1 << 16);
        }
    } else {
        int b2 = bid - 1024;
        int cob = b2 >> 3;
        int cib = (b2 & 7) * 64;
        for (int s = tid; s < 4608; s += 256) {
            int co = s / 576, r = s - co * 576;
            lds[co * 577 + r] = w[((size_t)(cob * 8 + co) * 512 + cib) * 9 + r];
        }
        __syncthreads();
        const size_t spl = (size_t)9 * 512 * 512;
        u32* w32 = (u32*)w3;
        int co = tid >> 5, cp = tid & 31;
        for (int kk = 0; kk < 9; kk++) {
            float v0 = lds[co * 577 + (2 * cp) * 9 + kk];
            float v1 = lds[co * 577 + (2 * cp + 1) * 9 + kk];
            ushort_t m0, m1, l0, l1;
            u32 hi = pack3(v0, v1, &m0, &m1, &l0, &l1);
            size_t base = ((size_t)kk * 512 + cob * 8 + co) * 512 + cib + 2 * cp;
            w32[base >> 1] = hi;
            w32[(base + spl) >> 1] = (u32)m0 | ((u32)m1 << 16);
            w32[(base + 2 * spl) >> 1] = (u32)l0 | ((u32)l1 << 16);
        }
    }
}

__global__ __launch_bounds__(256, 2) void k1_conv(const ushort_t* __restrict__ ft,
                                                  const ushort_t* __restrict__ w3,
                                                  float* __restrict__ nhwc) {
    __shared__ ushort_t lds16[3 * A_SPL2];
    int tid = threadIdx.x;
    int bid = blockIdx.x;
    int nt = (bid >> 1) & 1;
    int kh = (bid >> 2) & 1;
    int mt = ((bid >> 3) << 1) | (bid & 1);
    int b = mt >> 6, y = mt & 63;
    int nb = nt << 8;
    int ct0 = kh * 8;
    int lane = tid & 63;
    int w = tid >> 6;
    int wn = w << 6;
    int nlane = lane & 31;
    int kgrp8 = (lane >> 5) * 8;
    const size_t FT_SPL = (size_t)2 * 64 * 64 * 512;
    const size_t W3_SPL = (size_t)9 * 512 * 512;
    int sx = tid >> 2;
    int sq = tid & 3;
    f32x16 acc[2];
    f32x16 acc2[2];
#pragma unroll
    for (int ni = 0; ni < 2; ni++)
#pragma unroll
        for (int r = 0; r < 16; r++) { acc[ni][r] = 0.0f; acc2[ni][r] = 0.0f; }
    if (tid < 72) {
        int s = tid / 24, rem = tid % 24;
        int r = rem >> 3, rem2 = rem & 7;
        int side = rem2 >> 2, q = rem2 & 3;
        uint4 z = make_uint4(0, 0, 0, 0);
        *(uint4*)&lds16[s * A_SPL2 + (r * 66 + side * 65) * 40 + q * 8] = z;
    }
    uint4 pbA[9];
    auto loadA = [&](int ct) {
#pragma unroll
        for (int r = 0; r < 3; r++) {
            int yy = y - 1 + r;
            bool valid = (yy >= 0 && yy < 64);
            size_t rowbase = ((size_t)(b * 64 + (valid ? yy : 0)) * 64 + sx) * 512 + ct * 32 + sq * 8;
#pragma unroll
            for (int s = 0; s < 3; s++) {
                uint4 v = make_uint4(0, 0, 0, 0);
                if (valid) v = *(const uint4*)&ft[rowbase + (size_t)s * FT_SPL];
                pbA[r * 3 + s] = v;
            }
        }
    };
    auto writeA = [&]() {
#pragma unroll
        for (int r = 0; r < 3; r++)
#pragma unroll
            for (int s = 0; s < 3; s++)
                *(uint4*)&lds16[s * A_SPL2 + (r * 66 + sx + 1) * 40 + sq * 8] = pbA[r * 3 + s];
    };
    short8 breg[2][2][3];
    auto loadB = [&](int buf, int tap, int ks, int ct) {
#pragma unroll
        for (int ni = 0; ni < 2; ni++) {
            size_t cobase = ((size_t)(tap * 512 + nb + wn + ni * 32 + nlane)) * 512
                            + ct * 32 + ks * 16 + kgrp8;
#pragma unroll
            for (int s = 0; s < 3; s++)
                breg[buf][ni][s] = *(const short8*)&w3[(size_t)s * W3_SPL + cobase];
        }
    };
    loadA(ct0);
    loadB(0, 0, 0, ct0);
    for (int ct = ct0; ct < ct0 + 8; ct++) {
        __syncthreads();
        writeA();
        __syncthreads();
        if (ct + 1 < ct0 + 8) loadA(ct + 1);
#pragma unroll
        for (int u = 0; u < 18; u++) {
            int cur = u & 1, alt = cur ^ 1;
            if (u + 1 < 18) loadB(alt, (u + 1) >> 1, (u + 1) & 1, ct);
            else if (ct + 1 < ct0 + 8) loadB(alt, 0, 0, ct + 1);
            int tap = u >> 1, ks = u & 1;
            int ky = tap / 3, kx = tap - ky * 3;
            short8 af[3][2];
#pragma unroll
            for (int s = 0; s < 3; s++) {
#pragma unroll
                for (int mi = 0; mi < 2; mi++)
                    af[s][mi] = *(const short8*)&lds16[s * A_SPL2 +
                        (ky * 66 + mi * 32 + nlane + kx) * 40 + ks * 16 + kgrp8];
            }
#pragma unroll
            for (int t = 0; t < 6; t++) {
                const int sa_t[6] = {0, 0, 1, 0, 1, 2};
                const int sb_t[6] = {0, 1, 0, 2, 1, 0};
                int sa = sa_t[t], sb = sb_t[t];
#pragma unroll
                for (int ni = 0; ni < 2; ni++) {
                    acc[ni]  = __builtin_amdgcn_mfma_f32_32x32x16_bf16(
                        af[sa][0], breg[cur][ni][sb], acc[ni], 0, 0, 0);
                    acc2[ni] = __builtin_amdgcn_mfma_f32_32x32x16_bf16(
                        af[sa][1], breg[cur][ni][sb], acc2[ni], 0, 0, 0);
                }
            }
        }
    }
#pragma unroll
    for (int ni = 0; ni < 2; ni++) {
        int co = nb + wn + ni * 32 + nlane;
#pragma unroll
        for (int r = 0; r < 16; r++) {
            int xx = (r & 3) + 8 * (r >> 2) + 4 * (lane >> 5);
            atomicAdd(&nhwc[((size_t)(b * 64 + y) * 64 + xx) * 512 + co], acc[ni][r]);
            atomicAdd(&nhwc[((size_t)(b * 64 + y) * 64 + 32 + xx) * 512 + co], acc2[ni][r]);
        }
    }
}

__global__ __launch_bounds__(256) void k2_heads(const float* __restrict__ nhwc,
                                                const float* __restrict__ share_b,
                                                const float* __restrict__ cls_w,
                                                const float* __restrict__ cls_b,
                                                const float* __restrict__ reg_w,
                                                const float* __restrict__ reg_b,
                                                float* __restrict__ out,
                                                float* __restrict__ boxes_ws,
                                                u32* __restrict__ keys_ws,
                                                const int* d_imgh, const int* d_imgw) {
    int bid = blockIdx.x;
    int row = bid >> 2;
    int b = row >> 6, y = row & 63;
    int q = bid & 3;
    int p0 = q * 16;
    int tid = threadIdx.x;
    __shared__ float Al[16 * 68];
    __shared__ float Wl[64 * 64];
    __shared__ float Ob[54 * 16];
    int og = tid & 15, pg = tid >> 4;
    float acc[4];
#pragma unroll
    for (int j = 0; j < 4; j++) acc[j] = 0.0f;
    for (int cib = 0; cib < 512; cib += 64) {
        for (int s = tid; s < 1024; s += 256) {
            int kk = s & 63, pp = s >> 6;
            float v = nhwc[((size_t)(b * 64 + y) * 64 + p0 + pp) * 512 + cib + kk]
                      + share_b[cib + kk];
            Al[pp * 68 + kk] = fmaxf(v, 0.0f);
        }
        for (int s = tid; s < 64 * 64; s += 256) {
            int o = s >> 6, kk = s & 63;
            float wv = 0.0f;
            if (o < 18) wv = cls_w[o * 512 + cib + kk];
            else if (o < 54) wv = reg_w[(o - 18) * 512 + cib + kk];
            Wl[s] = wv;
        }
        __syncthreads();
        for (int kq = 0; kq < 16; kq++) {
            float4 a4 = *(const float4*)&Al[pg * 68 + kq * 4];
#pragma unroll
            for (int j = 0; j < 4; j++) {
                float4 w4 = *(const float4*)&Wl[(og * 4 + j) * 64 + kq * 4];
                acc[j] += a4.x * w4.x + a4.y * w4.y + a4.z * w4.z + a4.w * w4.w;
            }
        }
        __syncthreads();
    }
#pragma unroll
    for (int j = 0; j < 4; j++) {
        int o = og * 4 + j;
        if (o < 54) {
            float bvv = (o < 18) ? cls_b[o] : reg_b[o - 18];
            Ob[o * 16 + pg] = acc[j] + bvv;
        }
    }
    __syncthreads();
    float imgh = (float)d_imgh[0], imgw = (float)d_imgw[0];
    for (int task = tid; task < 144; task += 256) {
        int ta = task >> 4, p2 = task & 15;
        int x = p0 + p2;
        int a_idx = (y * 64 + x) * 9 + ta;
        int j = 0;
        bool myvalid = false;
#pragma unroll
        for (int tt = 0; tt < 9; tt++) {
            float c0, c1, c2, c3;
            anchor_base(tt, c0, c1, c2, c3);
            int ylo = (int)((-c0) / 16.0f) + 1;
            int yhi = (int)((imgh - c2) / 16.0f);
            int xlo = (int)((-c1) / 16.0f) + 1;
            int xhi = (int)((imgw - c3) / 16.0f);
            ylo = max(ylo, 0); yhi = min(yhi, 63);
            xlo = max(xlo, 0); xhi = min(xhi, 63);
            int Wt  = max(xhi - xlo + 1, 0);
            int nry = max(yhi - ylo + 1, 0);
            int rb  = min(max(y - ylo, 0), nry);
            bool vy = (y >= ylo) && (y <= yhi);
            int cb  = vy ? min(max(x - xlo, 0), Wt) : 0;
            bool val = vy && (x >= xlo) && (x <= xhi);
            j += rb * Wt + cb + ((tt < ta && val) ? 1 : 0);
            if (tt == ta) {
                myvalid = val;
                float4 o4;
                o4.x = c0 + 16.0f * y;
                o4.y = c1 + 16.0f * x;
                o4.z = c2 + 16.0f * y;
                o4.w = c3 + 16.0f * x;
                *(float4*)&out[OUT_ANC + a_idx * 4] = o4;
            }
        }
        if (!myvalid) continue;
        float c0 = Ob[(2 * ta) * 16 + p2], c1 = Ob[(2 * ta + 1) * 16 + p2];
        float m = fmaxf(c0, c1);
        float e0 = expf(c0 - m), e1 = expf(c1 - m);
        float sden = e0 + e1;
        float p0v = e0 / sden, p1v = e1 / sden;
        out[OUT_CLS + (size_t)(b * KANC + j) * 2 + 0] = p0v;
        out[OUT_CLS + (size_t)(b * KANC + j) * 2 + 1] = p1v;
        float l0 = Ob[(18 + 4 * ta + 0) * 16 + p2];
        float l1 = Ob[(18 + 4 * ta + 1) * 16 + p2];
        float l2 = Ob[(18 + 4 * ta + 2) * 16 + p2];
        float l3 = Ob[(18 + 4 * ta + 3) * 16 + p2];
        out[OUT_REG + (size_t)(b * KANC + j) * 4 + 0] = l0;
        out[OUT_REG + (size_t)(b * KANC + j) * 4 + 1] = l1;
        out[OUT_REG + (size_t)(b * KANC + j) * 4 + 2] = l2;
        out[OUT_REG + (size_t)(b * KANC + j) * 4 + 3] = l3;
        float b0, b1, b2, b3; anchor_base(ta, b0, b1, b2, b3);
        float ay1 = b0 + 16.0f * y, ax1 = b1 + 16.0f * x;
        float ay2 = b2 + 16.0f * y, ax2 = b3 + 16.0f * x;
        float hh = ay2 - ay1, wdt = ax2 - ax1;
        float cy = ay1 + 0.5f * hh, cx = ax1 + 0.5f * wdt;
        float ncy = l0 * hh + cy, ncx = l1 * wdt + cx;
        float nh = hh * expf(l2), nw = wdt * expf(l3);
        float by1 = fminf(fmaxf(ncy - 0.5f * nh, 0.0f), imgh);
        float bx1 = fminf(fmaxf(ncx - 0.5f * nw, 0.0f), imgw);
        float by2 = fminf(fmaxf(ncy + 0.5f * nh, 0.0f), imgh);
        float bx2 = fminf(fmaxf(ncx + 0.5f * nw, 0.0f), imgw);
        boxes_ws[(size_t)(b * KANC + j) * 4 + 0] = by1;
        boxes_ws[(size_t)(b * KANC + j) * 4 + 1] = bx1;
        boxes_ws[(size_t)(b * KANC + j) * 4 + 2] = by2;
        boxes_ws[(size_t)(b * KANC + j) * 4 + 3] = bx2;
        float hs = by2 - by1, wsz = bx2 - bx1;
        u32 key = 0;
        if (hs >= 16.0f && wsz >= 16.0f) key = __float_as_uint(p1v) + 1u;
        keys_ws[b * KANC + j] = key;
    }
}

__device__ __forceinline__ void suffix_scan(u32* suf, const u32* hist, int N, int tid) {
    for (int i = tid; i < N; i += 1024) suf[i] = hist[i];
    if (tid == 0) suf[N] = 0;
    __syncthreads();
    for (int off = 1; off < N; off <<= 1) {
        u32 add0 = 0, add1 = 0;
        int i0 = tid, i1 = tid + 1024;
        if (i0 < N) add0 = (i0 + off < N) ? suf[i0 + off] : 0;
        if (i1 < N) add1 = (i1 + off < N) ? suf[i1 + off] : 0;
        __syncthreads();
        if (i0 < N) suf[i0] += add0;
        if (i1 < N) suf[i1] += add1;
        __syncthreads();
    }
}

__global__ __launch_bounds__(1024) void k3_select(const u32* __restrict__ keys_ws,
                                                  const float* __restrict__ boxes_ws,
                                                  u32* __restrict__ topkey,
                                                  float* __restrict__ topbox) {
    int b = blockIdx.x, tid = threadIdx.x;
    const u32* keys = keys_ws + (size_t)b * KANC;
    __shared__ u64 sbuf[2048];
    __shared__ u32 hist[2048];
    __shared__ u32 suf[2049];
    __shared__ int Ps;
    __shared__ int cnt;
    u32* hist_p = (u32*)sbuf;
    int cpy = tid >> 7;
    for (int i = tid; i < 4096; i += 1024) hist_p[i] = 0;
    __syncthreads();
    for (int i = tid; i < KANC; i += 1024) atomicAdd(&hist_p[cpy * 512 + (keys[i] >> 22)], 1u);
    __syncthreads();
    for (int bin = tid; bin < 512; bin += 1024) {
        u32 s = 0;
#pragma unroll
        for (int c = 0; c < 8; c++) s += hist_p[c * 512 + bin];
        hist[bin] = s;
    }
    __syncthreads();
    suffix_scan(suf, hist, 512, tid);
    if (tid == 0) Ps = 0;
    __syncthreads();
    for (int i = tid; i < 512; i += 1024)
        if (suf[i] >= (u32)PRE && suf[i + 1] < (u32)PRE) Ps = i;
    __syncthreads();
    u32 P1 = (u32)Ps;
    u32 quota2 = (u32)PRE - suf[P1 + 1];
    __syncthreads();
    for (int i = tid; i < 2048; i += 1024) hist[i] = 0;
    __syncthreads();
    for (int i = tid; i < KANC; i += 1024) {
        u32 k = keys[i];
        if ((k >> 22) == P1) atomicAdd(&hist[(k >> 11) & 2047u], 1u);
    }
    __syncthreads();
    suffix_scan(suf, hist, 2048, tid);
    if (tid == 0) Ps = 0;
    __syncthreads();
    for (int i = tid; i < 2048; i += 1024)
        if (suf[i] >= quota2 && suf[i + 1] < quota2) Ps = i;
    __syncthreads();
    u32 P2 = (u32)Ps;
    u32 quota3 = quota2 - suf[P2 + 1];
    __syncthreads();
    u32 pref = (P1 << 11) | P2;
    for (int i = tid; i < 2048; i += 1024) hist[i] = 0;
    __syncthreads();
    for (int i = tid; i < KANC; i += 1024) {
        u32 k = keys[i];
        if ((k >> 11) == pref) atomicAdd(&hist[k & 2047u], 1u);
    }
    __syncthreads();
    suffix_scan(suf, hist, 2048, tid);
    if (tid == 0) Ps = 0;
    __syncthreads();
    for (int i = tid; i < 2048; i += 1024)
        if (suf[i] >= quota3 && suf[i + 1] < quota3) Ps = i;
    __syncthreads();
    u32 P3 = (u32)Ps;
    u32 T = (P1 << 22) | (P2 << 11) | P3;
    u32 Tm = (T < 1u) ? 1u : T;
    __syncthreads();
    for (int i = tid; i < 2048; i += 1024) sbuf[i] = 0ull;
    if (tid == 0) cnt = 0;
    __syncthreads();
    int lane = tid & 63;
    for (int i = tid; i < KANC + 1023; i += 1024) {
        u32 k = (i < KANC) ? keys[i] : 0u;
        bool p = (i < KANC) && (k >= Tm);
        u64 m = __ballot(p);
        if (m) {
            int ldr = __ffsll((unsigned long long)m) - 1;
            int base = 0;
            if (lane == ldr) base = atomicAdd(&cnt, __popcll(m));
            base = __shfl(base, ldr);
            if (p) {
                int pos = base + __popcll(m & ((1ull << lane) - 1ull));
                if (pos < 2048)
                    sbuf[pos] = ((u64)k << 32) | (u64)(0xFFFFFFFFu - (u32)i);
            }
        }
    }
    __syncthreads();
    for (int k2 = 2; k2 <= 2048; k2 <<= 1) {
        for (int j2 = k2 >> 1; j2 > 0; j2 >>= 1) {
            for (int i = tid; i < 2048; i += 1024) {
                int ixj = i ^ j2;
                if (ixj > i) {
                    u64 va = sbuf[i], vb = sbuf[ixj];
                    bool descRegion = ((i & k2) == 0);
                    if (descRegion ? (va < vb) : (va > vb)) {
                        sbuf[i] = vb; sbuf[ixj] = va;
                    }
                }
            }
            __syncthreads();
        }
    }
    for (int i = tid; i < PREP; i += 1024) {
        u64 v = sbuf[i];
        u32 kk = (u32)(v >> 32);
        u32 j = 0xFFFFFFFFu - (u32)(v & 0xFFFFFFFFull);
        bool good = (i < PRE) && (kk != 0);
        topkey[b * PREP + i] = good ? kk : 0;
        float4 bx = make_float4(0.0f, 0.0f, 0.0f, 0.0f);
        if (good) bx = *(const float4*)&boxes_ws[(size_t)(b * KANC + j) * 4];
        *(float4*)&topbox[(size_t)(b * PREP + i) * 4] = bx;
    }
}

__global__ __launch_bounds__(256) void k4_mask(const float* __restrict__ topbox,
                                               u64* __restrict__ mask) {
    int ib = blockIdx.y, b = blockIdx.z;
    int lane = threadIdx.x & 63;
    int jb = blockIdx.x * 4 + (threadIdx.x >> 6);
    if (jb < ib) {
        mask[(size_t)(b * PREP + ib * 64 + lane) * 32 + jb] = 0ull;
        return;
    }
    float4 bi = *(const float4*)&topbox[(size_t)(b * PREP + ib * 64 + lane) * 4];
    float4 bj = *(const float4*)&topbox[(size_t)(b * PREP + jb * 64 + lane) * 4];
    float ai = (bi.z - bi.x) * (bi.w - bi.y);
    float aj = (bj.z - bj.x) * (bj.w - bj.y);
    u64 word = 0;
    for (int ii = 0; ii < 64; ii++) {
        float y1 = __shfl(bi.x, ii), x1 = __shfl(bi.y, ii);
        float y2 = __shfl(bi.z, ii), x2 = __shfl(bi.w, ii);
        float aii = __shfl(ai, ii);
        float yy1 = fmaxf(y1, bj.x), xx1 = fmaxf(x1, bj.y);
        float yy2 = fminf(y2, bj.z), xx2 = fminf(x2, bj.w);
        float inter = fmaxf(yy2 - yy1, 0.0f) * fmaxf(xx2 - xx1, 0.0f);
        float iou = inter / (aii + aj - inter + 1e-9f);
        u64 bal = __ballot(iou > 0.7f);
        if (lane == ii) word = bal;
    }
    mask[(size_t)(b * PREP + ib * 64 + lane) * 32 + jb] = word;
}

__global__ __launch_bounds__(64) void k5_nms(const u32* __restrict__ topkey,
                                             const float* __restrict__ topbox,
                                             const u64* __restrict__ mask,
                                             float* __restrict__ out) {
    int b = blockIdx.x;
    int lane = threadIdx.x;
    __shared__ int kept[POST];
    u64 validw = 0;
    for (int it = 0; it < 32; it++) {
        u64 wv = __ballot(topkey[b * PREP + it * 64 + lane] != 0);
        if (lane == it) validw = wv;
    }
    const u64* mb = mask + (size_t)b * PREP * 32;
    u64 remv = 0;
    const int CH = 16;
    u64 bufA[CH], bufB[CH];
    auto loadRows = [&](u64* buf, int base) {
#pragma unroll
        for (int k = 0; k < CH; k++)
            buf[k] = (lane < 32) ? mb[(size_t)(base + k) * 32 + lane] : 0ull;
    };
    int nk = 0;
    auto process = [&](u64* buf, int base) {
        int wi = base >> 6, sh = base & 63;
        u64 supw = __shfl(remv, wi);
        u64 valw = __shfl(validw, wi);
        u32 cand = (u32)(((~supw & valw) >> sh) & 0xFFFFull);
        while (cand) {
            int k = __builtin_ctz(cand);
            cand &= cand - 1;
            int i = base + k;
            remv |= buf[k];
            u64 rw = __shfl(buf[k], wi);
            cand &= ~((u32)((rw >> sh) & 0xFFFFull));
            if (lane == 0) kept[nk] = i;
            nk++;
            if (nk == POST) break;
        }
    };
    loadRows(bufA, 0);
    for (int base = 0; base < PRE && nk < POST; base += 2 * CH) {
        loadRows(bufB, base + CH);
        process(bufA, base);
        if (nk < POST && base + CH < PRE) {
            if (base + 2 * CH < PRE) loadRows(bufA, base + 2 * CH);
            process(bufB, base + CH);
        }
    }
    __syncthreads();
    for (int s = lane; s < POST; s += 64) {
        float4 bx = make_float4(0.0f, 0.0f, 0.0f, 0.0f);
        if (s < nk) bx = *(const float4*)&topbox[(size_t)(b * PREP + kept[s]) * 4];
        *(float4*)&out[OUT_ROI + (size_t)(b * POST + s) * 4] = bx;
        out[OUT_RID + b * POST + s] = (float)b;
    }
}

extern "C" void kernel_launch(void* const* d_in, const int* in_sizes, int n_in,
                              void* d_out, int out_size, void* d_ws, size_t ws_size,
                              hipStream_t stream) {
    (void)in_sizes; (void)n_in; (void)out_size; (void)ws_size;
    const float* feat    = (const float*)d_in[0];
    const float* share_w = (const float*)d_in[1];
    const float* share_b = (const float*)d_in[2];
    const float* cls_w   = (const float*)d_in[3];
    const float* cls_b   = (const float*)d_in[4];
    const float* reg_w   = (const float*)d_in[5];
    const float* reg_b   = (const float*)d_in[6];
    const int*   imgh    = (const int*)d_in[7];
    const int*   imgw    = (const int*)d_in[8];
    float* out = (float*)d_out;
    char* ws = (char*)d_ws;
    float*     nhwc   = (float*)(ws + WS_NHWC);
    ushort_t*  ft     = (ushort_t*)(ws + WS_FT);
    ushort_t*  w3     = (ushort_t*)(ws + WS_W3);
    float*     boxes  = (float*)(ws + WS_BOXES);
    u32*       keys   = (u32*)(ws + WS_KEYS);
    float*     topbox = (float*)(ws + WS_TOPBOX);
    u32*       topkey = (u32*)(ws + WS_TOPKEY);
    u64*       maskp  = (u64*)(ws + WS_MASK);

    void* kargs[] = {
        (void*)&feat, (void*)&share_w, (void*)&share_b, (void*)&cls_w,
        (void*)&cls_b, (void*)&reg_w, (void*)&reg_b, (void*)&imgh,
        (void*)&imgw, (void*)&out, (void*)&nhwc, (void*)&ft, (void*)&w3,
        (void*)&boxes, (void*)&keys, (void*)&topbox, (void*)&topkey,
        (void*)&maskp
    };
    hipError_t err = hipLaunchCooperativeKernel((const void*)mega, dim3(512), dim3(256),
                                                kargs, 0, stream);
    if (err != hipSuccess) {
        // fallback: R10 6-kernel pipeline
        t12_pre<<<1536, 256, 0, stream>>>(feat, share_w, ft, w3, nhwc);
        k1_conv<<<512, 256, 0, stream>>>(ft, w3, nhwc);
        k2_heads<<<512, 256, 0, stream>>>(nhwc, share_b, cls_w, cls_b, reg_w, reg_b,
                                          out, boxes, keys, imgh, imgw);
        k3_select<<<2, 1024, 0, stream>>>(keys, boxes, topkey, topbox);
        k4_mask<<<dim3(8, 32, 2), 256, 0, stream>>>(topbox, maskp);
        k5_nms<<<2, 64, 0, stream>>>(topkey, topbox, maskp, out);
    }
}

// Round 12
// 620.879 us; speedup vs baseline: 1.6682x; 1.6682x over previous
//
#include <hip/hip_runtime.h>
#include <math.h>

typedef unsigned int u32;
typedef unsigned long long u64;
typedef unsigned short ushort_t;

typedef __attribute__((ext_vector_type(8))) short short8;
typedef __attribute__((ext_vector_type(16))) float f32x16;

#define KANC 18376
#define PRE 2000
#define PREP 2048
#define POST 300

#define OUT_CLS 0
#define OUT_REG 73504
#define OUT_ROI 220512
#define OUT_RID 222912
#define OUT_ANC 223512

// ws byte offsets
#define WS_NHWC   0u
#define WS_FT     16777216u
#define WS_W3     41943040u
#define WS_VPOS   56098816u
#define WS_BOXES  56246272u
#define WS_KEYS   56834304u
#define WS_TOPBOX 56981312u
#define WS_TOPKEY 57046848u
#define WS_MASK   57063232u

// k1 LDS: A only, 3 splits x 3 rows x 66 xi x (32ci pad to 40)
#define A_SPL2 7920   // ushorts per split

__device__ __forceinline__ ushort_t f2bf(float f) {
    u32 u = __float_as_uint(f);
    u32 r = (u + 0x7FFFu + ((u >> 16) & 1u)) >> 16;
    return (ushort_t)r;
}
__device__ __forceinline__ float bf2f(ushort_t h) {
    return __uint_as_float(((u32)h) << 16);
}
__device__ __forceinline__ u32 pack3(float v0, float v1, ushort_t* m0, ushort_t* m1,
                                     ushort_t* l0, ushort_t* l1) {
    ushort_t h0 = f2bf(v0);
    float r = v0 - bf2f(h0);
    *m0 = f2bf(r);
    *l0 = f2bf(r - bf2f(*m0));
    ushort_t h1 = f2bf(v1);
    float r1 = v1 - bf2f(h1);
    *m1 = f2bf(r1);
    *l1 = f2bf(r1 - bf2f(*m1));
    return (u32)h0 | ((u32)h1 << 16);
}

// hardcoded correctly-rounded doubles: sqrt(0.5), 1, sqrt(2)
__device__ __forceinline__ void anchor_base(int t, float& y1, float& x1, float& y2, float& x2) {
    const double SQ[3] = {0.7071067811865476, 1.0, 1.4142135623730951};
    const double SC[3] = {8.0, 16.0, 32.0};
    int ri = t / 3, si = t % 3;
    double h = 16.0 * SC[si] * SQ[ri];
    double w = 16.0 * SC[si] * SQ[2 - ri];
    y1 = (float)(8.0 - h * 0.5);
    x1 = (float)(8.0 - w * 0.5);
    y2 = (float)(8.0 + h * 0.5);
    x2 = (float)(8.0 + w * 0.5);
}

// ---------------- T12: fused input transforms + nhwc zeroing ----------------
__global__ __launch_bounds__(256) void t12_pre(const float* __restrict__ feat,
                                               const float* __restrict__ w,
                                               ushort_t* __restrict__ ft,
                                               ushort_t* __restrict__ w3,
                                               float* __restrict__ nhwc) {
    __shared__ float lds[8 * 577];
    int tid = threadIdx.x;
    int bid = blockIdx.x;
    if (bid < 1024) {
        float4 z4 = make_float4(0.f, 0.f, 0.f, 0.f);
        float4* nz = (float4*)nhwc + (size_t)bid * 1024;
        for (int i = tid; i < 1024; i += 256) nz[i] = z4;

        int by = bid >> 3;            // b*64 + y
        int b = by >> 6, y = by & 63;
        int ci0 = (bid & 7) * 64;
        for (int it = 0; it < 16; it++) {
            int idx = it * 256 + tid;
            int ci = idx >> 6, x = idx & 63;
            lds[ci * 65 + x] = feat[((size_t)(b * 512 + ci0 + ci) * 64 + y) * 64 + x];
        }
        __syncthreads();
        const size_t spl = (size_t)2 * 64 * 64 * 512;
        u32* ft32 = (u32*)ft;
        for (int it = 0; it < 8; it++) {
            int idx = it * 256 + tid;
            int x = idx >> 5, cp = idx & 31;
            float v0 = lds[(2 * cp) * 65 + x];
            float v1 = lds[(2 * cp + 1) * 65 + x];
            ushort_t m0, m1, l0, l1;
            u32 hi = pack3(v0, v1, &m0, &m1, &l0, &l1);
            size_t base = ((size_t)(b * 64 + y) * 64 + x) * 512 + ci0 + 2 * cp;
            ft32[base >> 1] = hi;
            ft32[(base + spl) >> 1] = (u32)m0 | ((u32)m1 << 16);
            ft32[(base + 2 * spl) >> 1] = (u32)l0 | ((u32)l1 << 16);
        }
    } else {
        int b2 = bid - 1024;          // 512 blocks: 64 co-blocks x 8 ci-blocks
        int cob = b2 >> 3;
        int cib = (b2 & 7) * 64;
        for (int s = tid; s < 4608; s += 256) {
            int co = s / 576, r = s - co * 576;
            lds[co * 577 + r] = w[((size_t)(cob * 8 + co) * 512 + cib) * 9 + r];
        }
        __syncthreads();
        const size_t spl = (size_t)9 * 512 * 512;
        u32* w32 = (u32*)w3;
        int co = tid >> 5, cp = tid & 31;
        for (int kk = 0; kk < 9; kk++) {
            float v0 = lds[co * 577 + (2 * cp) * 9 + kk];
            float v1 = lds[co * 577 + (2 * cp + 1) * 9 + kk];
            ushort_t m0, m1, l0, l1;
            u32 hi = pack3(v0, v1, &m0, &m1, &l0, &l1);
            size_t base = ((size_t)kk * 512 + cob * 8 + co) * 512 + cib + 2 * cp;
            w32[base >> 1] = hi;
            w32[(base + spl) >> 1] = (u32)m0 | ((u32)m1 << 16);
            w32[(base + 2 * spl) >> 1] = (u32)l0 | ((u32)l1 << 16);
        }
    }
}

// ---------------- K1: 3x3 conv 512->512, bf16x3, 32x32x16 MFMA (R6 structure) ----------------
// Grid 512 = 128 mt x 2 nt x 2 kh. bid%8 fixes (nt,kh,mt_lsb) -> per-XCD 3.54MB
// weight slice L2-resident. Wave covers 64 co (ni=2): 6 A-ds_reads feed 24 MFMAs.
// Defended optimum (R6/R9: ~261us, MfmaUtil ~39%). Escape attempts all regressed:
// R7 split-K4 (atomic+fetch amplification), R8 x-split (B amplification + L2 thrash),
// R11 coop-fusion (phase-shape constraints). Partial sums atomicAdd into zeroed nhwc.
__global__ __launch_bounds__(256, 2) void k1_conv(const ushort_t* __restrict__ ft,
                                                  const ushort_t* __restrict__ w3,
                                                  float* __restrict__ nhwc) {
    __shared__ ushort_t lds16[3 * A_SPL2];   // 47520 B
    int tid = threadIdx.x;
    int bid = blockIdx.x;
    int nt = (bid >> 1) & 1;
    int kh = (bid >> 2) & 1;
    int mt = ((bid >> 3) << 1) | (bid & 1);  // 0..127 = b*64 + y
    int b = mt >> 6, y = mt & 63;
    int nb = nt << 8;
    int ct0 = kh * 8;

    int lane = tid & 63;
    int w = tid >> 6;                 // wave 0..3
    int wn = w << 6;                  // 64 co per wave
    int nlane = lane & 31;
    int kgrp8 = (lane >> 5) * 8;

    const size_t FT_SPL = (size_t)2 * 64 * 64 * 512;
    const size_t W3_SPL = (size_t)9 * 512 * 512;

    int sx = tid >> 2;
    int sq = tid & 3;

    f32x16 acc[2];
    f32x16 acc2[2];
#pragma unroll
    for (int ni = 0; ni < 2; ni++)
#pragma unroll
        for (int r = 0; r < 16; r++) { acc[ni][r] = 0.0f; acc2[ni][r] = 0.0f; }

    // zero x-halo columns xi=0,65
    if (tid < 72) {
        int s = tid / 24, rem = tid % 24;
        int r = rem >> 3, rem2 = rem & 7;
        int side = rem2 >> 2, q = rem2 & 3;
        uint4 z = make_uint4(0, 0, 0, 0);
        *(uint4*)&lds16[s * A_SPL2 + (r * 66 + side * 65) * 40 + q * 8] = z;
    }

    uint4 pbA[9];
    auto loadA = [&](int ct) {
#pragma unroll
        for (int r = 0; r < 3; r++) {
            int yy = y - 1 + r;
            bool valid = (yy >= 0 && yy < 64);
            size_t rowbase = ((size_t)(b * 64 + (valid ? yy : 0)) * 64 + sx) * 512 + ct * 32 + sq * 8;
#pragma unroll
            for (int s = 0; s < 3; s++) {
                uint4 v = make_uint4(0, 0, 0, 0);
                if (valid) v = *(const uint4*)&ft[rowbase + (size_t)s * FT_SPL];
                pbA[r * 3 + s] = v;
            }
        }
    };
    auto writeA = [&]() {
#pragma unroll
        for (int r = 0; r < 3; r++)
#pragma unroll
            for (int s = 0; s < 3; s++)
                *(uint4*)&lds16[s * A_SPL2 + (r * 66 + sx + 1) * 40 + sq * 8] = pbA[r * 3 + s];
    };

    short8 breg[2][2][3];   // [buf][ni][split]
    auto loadB = [&](int buf, int tap, int ks, int ct) {
#pragma unroll
        for (int ni = 0; ni < 2; ni++) {
            size_t cobase = ((size_t)(tap * 512 + nb + wn + ni * 32 + nlane)) * 512
                            + ct * 32 + ks * 16 + kgrp8;
#pragma unroll
            for (int s = 0; s < 3; s++)
                breg[buf][ni][s] = *(const short8*)&w3[(size_t)s * W3_SPL + cobase];
        }
    };

    loadA(ct0);
    loadB(0, 0, 0, ct0);

    for (int ct = ct0; ct < ct0 + 8; ct++) {
        __syncthreads();
        writeA();
        __syncthreads();
        if (ct + 1 < ct0 + 8) loadA(ct + 1);

#pragma unroll
        for (int u = 0; u < 18; u++) {
            int cur = u & 1, alt = cur ^ 1;   // compile-time after unroll; 18 even -> parity stable
            if (u + 1 < 18) loadB(alt, (u + 1) >> 1, (u + 1) & 1, ct);
            else if (ct + 1 < ct0 + 8) loadB(alt, 0, 0, ct + 1);
            int tap = u >> 1, ks = u & 1;
            int ky = tap / 3, kx = tap - ky * 3;

            short8 af[3][2];
#pragma unroll
            for (int s = 0; s < 3; s++) {
#pragma unroll
                for (int mi = 0; mi < 2; mi++)
                    af[s][mi] = *(const short8*)&lds16[s * A_SPL2 +
                        (ky * 66 + mi * 32 + nlane + kx) * 40 + ks * 16 + kgrp8];
            }
#pragma unroll
            for (int t = 0; t < 6; t++) {
                const int sa_t[6] = {0, 0, 1, 0, 1, 2};
                const int sb_t[6] = {0, 1, 0, 2, 1, 0};
                int sa = sa_t[t], sb = sb_t[t];
#pragma unroll
                for (int ni = 0; ni < 2; ni++) {
                    acc[ni]  = __builtin_amdgcn_mfma_f32_32x32x16_bf16(
                        af[sa][0], breg[cur][ni][sb], acc[ni], 0, 0, 0);
                    acc2[ni] = __builtin_amdgcn_mfma_f32_32x32x16_bf16(
                        af[sa][1], breg[cur][ni][sb], acc2[ni], 0, 0, 0);
                }
            }
        }
    }

    // epilogue: atomic partial-sum accumulate
#pragma unroll
    for (int ni = 0; ni < 2; ni++) {
        int co = nb + wn + ni * 32 + nlane;
#pragma unroll
        for (int r = 0; r < 16; r++) {
            int xx = (r & 3) + 8 * (r >> 2) + 4 * (lane >> 5);
            atomicAdd(&nhwc[((size_t)(b * 64 + y) * 64 + xx) * 512 + co], acc[ni][r]);
            atomicAdd(&nhwc[((size_t)(b * 64 + y) * 64 + 32 + xx) * 512 + co], acc2[ni][r]);
        }
    }
}

// ---------------- K2: heads + softmax + decode + keys + anchors/vpos (k0 fused) ----------------
__global__ __launch_bounds__(256) void k2_heads(const float* __restrict__ nhwc,
                                                const float* __restrict__ share_b,
                                                const float* __restrict__ cls_w,
                                                const float* __restrict__ cls_b,
                                                const float* __restrict__ reg_w,
                                                const float* __restrict__ reg_b,
                                                float* __restrict__ out,
                                                float* __restrict__ boxes_ws,
                                                u32* __restrict__ keys_ws,
                                                const int* d_imgh, const int* d_imgw) {
    int bid = blockIdx.x;
    int row = bid >> 1;             // b*64 + y
    int b = row >> 6, y = row & 63;
    int h = bid & 1;                // px half
    int p0 = h * 32;
    int tid = threadIdx.x;
    __shared__ float Al[32 * 68];
    __shared__ float Wl[64 * 64];
    __shared__ float Ob[54 * 32];
    int og = tid & 15, pg = tid >> 4;
    float acc[2][4];
#pragma unroll
    for (int pp = 0; pp < 2; pp++)
#pragma unroll
        for (int j = 0; j < 4; j++) acc[pp][j] = 0.0f;

    for (int cib = 0; cib < 512; cib += 64) {
        for (int s = tid; s < 2048; s += 256) {
            int kk = s & 63, pp = s >> 6;
            float v = nhwc[((size_t)(b * 64 + y) * 64 + p0 + pp) * 512 + cib + kk]
                      + share_b[cib + kk];
            Al[pp * 68 + kk] = fmaxf(v, 0.0f);
        }
        for (int s = tid; s < 64 * 64; s += 256) {
            int o = s >> 6, kk = s & 63;
            float wv = 0.0f;
            if (o < 18) wv = cls_w[o * 512 + cib + kk];
            else if (o < 54) wv = reg_w[(o - 18) * 512 + cib + kk];
            Wl[s] = wv;
        }
        __syncthreads();
        for (int kq = 0; kq < 16; kq++) {
            float4 a0 = *(const float4*)&Al[(pg * 2) * 68 + kq * 4];
            float4 a1 = *(const float4*)&Al[(pg * 2 + 1) * 68 + kq * 4];
#pragma unroll
            for (int j = 0; j < 4; j++) {
                float4 w4 = *(const float4*)&Wl[(og * 4 + j) * 64 + kq * 4];
                acc[0][j] += a0.x * w4.x + a0.y * w4.y + a0.z * w4.z + a0.w * w4.w;
                acc[1][j] += a1.x * w4.x + a1.y * w4.y + a1.z * w4.z + a1.w * w4.w;
            }
        }
        __syncthreads();
    }
#pragma unroll
    for (int pp = 0; pp < 2; pp++)
#pragma unroll
        for (int j = 0; j < 4; j++) {
            int o = og * 4 + j;
            if (o < 54) {
                float bvv = (o < 18) ? cls_b[o] : reg_b[o - 18];
                Ob[o * 32 + pg * 2 + pp] = acc[pp][j] + bvv;
            }
        }
    __syncthreads();
    float imgh = (float)d_imgh[0], imgw = (float)d_imgw[0];
    for (int task = tid; task < 288; task += 256) {
        int ta = task >> 5, p2 = task & 31;
        int x = p0 + p2;
        int a_idx = (y * 64 + x) * 9 + ta;
        int j = 0;
        bool myvalid = false;
#pragma unroll
        for (int tt = 0; tt < 9; tt++) {
            float c0, c1, c2, c3;
            anchor_base(tt, c0, c1, c2, c3);
            int ylo = (int)((-c0) / 16.0f) + 1;
            int yhi = (int)((imgh - c2) / 16.0f);
            int xlo = (int)((-c1) / 16.0f) + 1;
            int xhi = (int)((imgw - c3) / 16.0f);
            ylo = max(ylo, 0); yhi = min(yhi, 63);
            xlo = max(xlo, 0); xhi = min(xhi, 63);
            int Wt  = max(xhi - xlo + 1, 0);
            int nry = max(yhi - ylo + 1, 0);
            int rb  = min(max(y - ylo, 0), nry);
            bool vy = (y >= ylo) && (y <= yhi);
            int cb  = vy ? min(max(x - xlo, 0), Wt) : 0;
            bool val = vy && (x >= xlo) && (x <= xhi);
            j += rb * Wt + cb + ((tt < ta && val) ? 1 : 0);
            if (tt == ta) {
                myvalid = val;
                float4 o4;
                o4.x = c0 + 16.0f * y;
                o4.y = c1 + 16.0f * x;
                o4.z = c2 + 16.0f * y;
                o4.w = c3 + 16.0f * x;
                *(float4*)&out[OUT_ANC + a_idx * 4] = o4;
            }
        }
        if (!myvalid) continue;
        float c0 = Ob[(2 * ta) * 32 + p2], c1 = Ob[(2 * ta + 1) * 32 + p2];
        float m = fmaxf(c0, c1);
        float e0 = expf(c0 - m), e1 = expf(c1 - m);
        float sden = e0 + e1;
        float p0v = e0 / sden, p1v = e1 / sden;
        out[OUT_CLS + (size_t)(b * KANC + j) * 2 + 0] = p0v;
        out[OUT_CLS + (size_t)(b * KANC + j) * 2 + 1] = p1v;
        float l0 = Ob[(18 + 4 * ta + 0) * 32 + p2];
        float l1 = Ob[(18 + 4 * ta + 1) * 32 + p2];
        float l2 = Ob[(18 + 4 * ta + 2) * 32 + p2];
        float l3 = Ob[(18 + 4 * ta + 3) * 32 + p2];
        out[OUT_REG + (size_t)(b * KANC + j) * 4 + 0] = l0;
        out[OUT_REG + (size_t)(b * KANC + j) * 4 + 1] = l1;
        out[OUT_REG + (size_t)(b * KANC + j) * 4 + 2] = l2;
        out[OUT_REG + (size_t)(b * KANC + j) * 4 + 3] = l3;
        float b0, b1, b2, b3; anchor_base(ta, b0, b1, b2, b3);
        float ay1 = b0 + 16.0f * y, ax1 = b1 + 16.0f * x;
        float ay2 = b2 + 16.0f * y, ax2 = b3 + 16.0f * x;
        float hh = ay2 - ay1, wdt = ax2 - ax1;
        float cy = ay1 + 0.5f * hh, cx = ax1 + 0.5f * wdt;
        float ncy = l0 * hh + cy, ncx = l1 * wdt + cx;
        float nh = hh * expf(l2), nw = wdt * expf(l3);
        float by1 = fminf(fmaxf(ncy - 0.5f * nh, 0.0f), imgh);
        float bx1 = fminf(fmaxf(ncx - 0.5f * nw, 0.0f), imgw);
        float by2 = fminf(fmaxf(ncy + 0.5f * nh, 0.0f), imgh);
        float bx2 = fminf(fmaxf(ncx + 0.5f * nw, 0.0f), imgw);
        boxes_ws[(size_t)(b * KANC + j) * 4 + 0] = by1;
        boxes_ws[(size_t)(b * KANC + j) * 4 + 1] = bx1;
        boxes_ws[(size_t)(b * KANC + j) * 4 + 2] = by2;
        boxes_ws[(size_t)(b * KANC + j) * 4 + 3] = bx2;
        float hs = by2 - by1, wsz = bx2 - bx1;
        u32 key = 0;
        if (hs >= 16.0f && wsz >= 16.0f) key = __float_as_uint(p1v) + 1u;
        keys_ws[b * KANC + j] = key;
    }
}

// ---------------- K3: exact top-2000, radix 9/11/11 bits, conflict-free histograms ----------------
__device__ __forceinline__ void suffix_scan(u32* suf, const u32* hist, int N, int tid) {
    for (int i = tid; i < N; i += 1024) suf[i] = hist[i];
    if (tid == 0) suf[N] = 0;
    __syncthreads();
    for (int off = 1; off < N; off <<= 1) {
        u32 add0 = 0, add1 = 0;
        int i0 = tid, i1 = tid + 1024;
        if (i0 < N) add0 = (i0 + off < N) ? suf[i0 + off] : 0;
        if (i1 < N) add1 = (i1 + off < N) ? suf[i1 + off] : 0;
        __syncthreads();
        if (i0 < N) suf[i0] += add0;
        if (i1 < N) suf[i1] += add1;
        __syncthreads();
    }
}

__global__ __launch_bounds__(1024) void k3_select(const u32* __restrict__ keys_ws,
                                                  const float* __restrict__ boxes_ws,
                                                  u32* __restrict__ topkey,
                                                  float* __restrict__ topbox) {
    int b = blockIdx.x, tid = threadIdx.x;
    const u32* keys = keys_ws + (size_t)b * KANC;
    __shared__ u64 sbuf[2048];
    __shared__ u32 hist[2048];
    __shared__ u32 suf[2049];
    __shared__ int Ps;
    __shared__ int cnt;

    // level 1: bits [30:22] (512 bins), 8 private copies aliased over sbuf
    u32* hist_p = (u32*)sbuf;
    int cpy = tid >> 7;
    for (int i = tid; i < 4096; i += 1024) hist_p[i] = 0;
    __syncthreads();
    for (int i = tid; i < KANC; i += 1024) atomicAdd(&hist_p[cpy * 512 + (keys[i] >> 22)], 1u);
    __syncthreads();
    for (int bin = tid; bin < 512; bin += 1024) {
        u32 s = 0;
#pragma unroll
        for (int c = 0; c < 8; c++) s += hist_p[c * 512 + bin];
        hist[bin] = s;
    }
    __syncthreads();
    suffix_scan(suf, hist, 512, tid);
    if (tid == 0) Ps = 0;
    __syncthreads();
    for (int i = tid; i < 512; i += 1024)
        if (suf[i] >= (u32)PRE && suf[i + 1] < (u32)PRE) Ps = i;
    __syncthreads();
    u32 P1 = (u32)Ps;
    u32 quota2 = (u32)PRE - suf[P1 + 1];
    __syncthreads();

    // level 2: bits [21:11] (2048 bins) within P1
    for (int i = tid; i < 2048; i += 1024) hist[i] = 0;
    __syncthreads();
    for (int i = tid; i < KANC; i += 1024) {
        u32 k = keys[i];
        if ((k >> 22) == P1) atomicAdd(&hist[(k >> 11) & 2047u], 1u);
    }
    __syncthreads();
    suffix_scan(suf, hist, 2048, tid);
    if (tid == 0) Ps = 0;
    __syncthreads();
    for (int i = tid; i < 2048; i += 1024)
        if (suf[i] >= quota2 && suf[i + 1] < quota2) Ps = i;
    __syncthreads();
    u32 P2 = (u32)Ps;
    u32 quota3 = quota2 - suf[P2 + 1];
    __syncthreads();

    // level 3: bits [10:0] (2048 bins) within (P1,P2)
    u32 pref = (P1 << 11) | P2;
    for (int i = tid; i < 2048; i += 1024) hist[i] = 0;
    __syncthreads();
    for (int i = tid; i < KANC; i += 1024) {
        u32 k = keys[i];
        if ((k >> 11) == pref) atomicAdd(&hist[k & 2047u], 1u);
    }
    __syncthreads();
    suffix_scan(suf, hist, 2048, tid);
    if (tid == 0) Ps = 0;
    __syncthreads();
    for (int i = tid; i < 2048; i += 1024)
        if (suf[i] >= quota3 && suf[i + 1] < quota3) Ps = i;
    __syncthreads();
    u32 P3 = (u32)Ps;
    u32 T = (P1 << 22) | (P2 << 11) | P3;
    u32 Tm = (T < 1u) ? 1u : T;

    // gather >= Tm with wave-aggregated atomics
    __syncthreads();
    for (int i = tid; i < 2048; i += 1024) sbuf[i] = 0ull;
    if (tid == 0) cnt = 0;
    __syncthreads();
    int lane = tid & 63;
    for (int i = tid; i < KANC + 1023; i += 1024) {
        u32 k = (i < KANC) ? keys[i] : 0u;
        bool p = (i < KANC) && (k >= Tm);
        u64 m = __ballot(p);
        if (m) {
            int ldr = __ffsll((unsigned long long)m) - 1;
            int base = 0;
            if (lane == ldr) base = atomicAdd(&cnt, __popcll(m));
            base = __shfl(base, ldr);
            if (p) {
                int pos = base + __popcll(m & ((1ull << lane) - 1ull));
                if (pos < 2048)
                    sbuf[pos] = ((u64)k << 32) | (u64)(0xFFFFFFFFu - (u32)i);
            }
        }
    }
    __syncthreads();

    // bitonic sort descending, 2048 u64
    for (int k2 = 2; k2 <= 2048; k2 <<= 1) {
        for (int j2 = k2 >> 1; j2 > 0; j2 >>= 1) {
            for (int i = tid; i < 2048; i += 1024) {
                int ixj = i ^ j2;
                if (ixj > i) {
                    u64 va = sbuf[i], vb = sbuf[ixj];
                    bool descRegion = ((i & k2) == 0);
                    if (descRegion ? (va < vb) : (va > vb)) {
                        sbuf[i] = vb; sbuf[ixj] = va;
                    }
                }
            }
            __syncthreads();
        }
    }

    for (int i = tid; i < PREP; i += 1024) {
        u64 v = sbuf[i];
        u32 kk = (u32)(v >> 32);
        u32 j = 0xFFFFFFFFu - (u32)(v & 0xFFFFFFFFull);
        bool good = (i < PRE) && (kk != 0);
        topkey[b * PREP + i] = good ? kk : 0;
        float4 bx = make_float4(0.0f, 0.0f, 0.0f, 0.0f);
        if (good) bx = *(const float4*)&boxes_ws[(size_t)(b * KANC + j) * 4];
        *(float4*)&topbox[(size_t)(b * PREP + i) * 4] = bx;
    }
}

// ---------------- K4: NMS suppression bitmask (upper triangle only) ----------------
__global__ __launch_bounds__(64) void k4_mask(const float* __restrict__ topbox,
                                              u64* __restrict__ mask) {
    int jb = blockIdx.x, ib = blockIdx.y, b = blockIdx.z;
    int lane = threadIdx.x;
    if (jb < ib) {
        mask[(size_t)(b * PREP + ib * 64 + lane) * 32 + jb] = 0ull;
        return;
    }
    float4 bi = *(const float4*)&topbox[(size_t)(b * PREP + ib * 64 + lane) * 4];
    float4 bj = *(const float4*)&topbox[(size_t)(b * PREP + jb * 64 + lane) * 4];
    float ai = (bi.z - bi.x) * (bi.w - bi.y);
    float aj = (bj.z - bj.x) * (bj.w - bj.y);
    u64 word = 0;
    for (int ii = 0; ii < 64; ii++) {
        float y1 = __shfl(bi.x, ii), x1 = __shfl(bi.y, ii);
        float y2 = __shfl(bi.z, ii), x2 = __shfl(bi.w, ii);
        float aii = __shfl(ai, ii);
        float yy1 = fmaxf(y1, bj.x), xx1 = fmaxf(x1, bj.y);
        float yy2 = fminf(y2, bj.z), xx2 = fminf(x2, bj.w);
        float inter = fmaxf(yy2 - yy1, 0.0f) * fmaxf(xx2 - xx1, 0.0f);
        float iou = inter / (aii + aj - inter + 1e-9f);
        u64 bal = __ballot(iou > 0.7f);
        if (lane == ii) word = bal;
    }
    mask[(size_t)(b * PREP + ib * 64 + lane) * 32 + jb] = word;
}

// ---------------- K5: greedy scan via candidate bitmask + ctz ----------------
__global__ __launch_bounds__(64) void k5_nms(const u32* __restrict__ topkey,
                                             const float* __restrict__ topbox,
                                             const u64* __restrict__ mask,
                                             float* __restrict__ out) {
    int b = blockIdx.x;
    int lane = threadIdx.x;
    __shared__ int kept[POST];

    u64 validw = 0;
    for (int it = 0; it < 32; it++) {
        u64 wv = __ballot(topkey[b * PREP + it * 64 + lane] != 0);
        if (lane == it) validw = wv;
    }

    const u64* mb = mask + (size_t)b * PREP * 32;
    u64 remv = 0;
    const int CH = 16;
    u64 bufA[CH], bufB[CH];
    auto loadRows = [&](u64* buf, int base) {
#pragma unroll
        for (int k = 0; k < CH; k++)
            buf[k] = (lane < 32) ? mb[(size_t)(base + k) * 32 + lane] : 0ull;
    };
    int nk = 0;
    auto process = [&](u64* buf, int base) {
        int wi = base >> 6, sh = base & 63;
        u64 supw = __shfl(remv, wi);
        u64 valw = __shfl(validw, wi);
        u32 cand = (u32)(((~supw & valw) >> sh) & 0xFFFFull);
        while (cand) {
            int k = __builtin_ctz(cand);
            cand &= cand - 1;
            int i = base + k;
            remv |= buf[k];
            u64 rw = __shfl(buf[k], wi);
            cand &= ~((u32)((rw >> sh) & 0xFFFFull));
            if (lane == 0) kept[nk] = i;
            nk++;
            if (nk == POST) break;
        }
    };

    loadRows(bufA, 0);
    for (int base = 0; base < PRE && nk < POST; base += 2 * CH) {
        loadRows(bufB, base + CH);
        process(bufA, base);
        if (nk < POST && base + CH < PRE) {
            if (base + 2 * CH < PRE) loadRows(bufA, base + 2 * CH);
            process(bufB, base + CH);
        }
    }
    __syncthreads();
    for (int s = lane; s < POST; s += 64) {
        float4 bx = make_float4(0.0f, 0.0f, 0.0f, 0.0f);
        if (s < nk) bx = *(const float4*)&topbox[(size_t)(b * PREP + kept[s]) * 4];
        *(float4*)&out[OUT_ROI + (size_t)(b * POST + s) * 4] = bx;
        out[OUT_RID + b * POST + s] = (float)b;
    }
}

extern "C" void kernel_launch(void* const* d_in, const int* in_sizes, int n_in,
                              void* d_out, int out_size, void* d_ws, size_t ws_size,
                              hipStream_t stream) {
    (void)in_sizes; (void)n_in; (void)out_size; (void)ws_size;
    const float* feat    = (const float*)d_in[0];
    const float* share_w = (const float*)d_in[1];
    const float* share_b = (const float*)d_in[2];
    const float* cls_w   = (const float*)d_in[3];
    const float* cls_b   = (const float*)d_in[4];
    const float* reg_w   = (const float*)d_in[5];
    const float* reg_b   = (const float*)d_in[6];
    const int*   imgh    = (const int*)d_in[7];
    const int*   imgw    = (const int*)d_in[8];
    float* out = (float*)d_out;
    char* ws = (char*)d_ws;
    float*     nhwc   = (float*)(ws + WS_NHWC);
    ushort_t*  ft     = (ushort_t*)(ws + WS_FT);
    ushort_t*  w3     = (ushort_t*)(ws + WS_W3);
    float*     boxes  = (float*)(ws + WS_BOXES);
    u32*       keys   = (u32*)(ws + WS_KEYS);
    float*     topbox = (float*)(ws + WS_TOPBOX);
    u32*       topkey = (u32*)(ws + WS_TOPKEY);
    u64*       maskp  = (u64*)(ws + WS_MASK);

    t12_pre<<<1536, 256, 0, stream>>>(feat, share_w, ft, w3, nhwc);
    k1_conv<<<512, 256, 0, stream>>>(ft, w3, nhwc);
    k2_heads<<<256, 256, 0, stream>>>(nhwc, share_b, cls_w, cls_b, reg_w, reg_b,
                                      out, boxes, keys, imgh, imgw);
    k3_select<<<2, 1024, 0, stream>>>(keys, boxes, topkey, topbox);
    k4_mask<<<dim3(32, 32, 2), 64, 0, stream>>>(topbox, maskp);
    k5_nms<<<2, 64, 0, stream>>>(topkey, topbox, maskp, out);
}